// Round 8
// baseline (8018.262 us; speedup 1.0000x reference)
//
#include <hip/hip_runtime.h>

#define N_CLOUDS 16
#define PTS      16384
#define M        4096
#define FPS_THREADS  1024
#define NWAVES   (FPS_THREADS / 64)   // 16 waves
#define PPT      16                   // consecutive (sorted-order) points per thread
#define SORT_THREADS 1024

typedef float v2f __attribute__((ext_vector_type(2)));
typedef unsigned long long u64;
typedef unsigned int u32;
typedef unsigned short u16;

// Round-12: EXACT speculative dual-step, fixed.
// r7's failure: g2 was built from chunk maxima only -> missed the winner
// chunk's runner-up -> wrong b2 emitted when global #2 shared w1's chunk.
// Fixes:
//  (1) exact global #2: per-lane chunk TOP-2 (strict >, ascending-orig slots
//      = exact u64-key order); wave #2 = max(winner lane's #2, others' #1)
//      via substitute+CHAIN6; cross-wave substitutes winner wave's #2.
//  (2) tie-safety: two-stage commit. Stage1 = w1-only update (ALWAYS the
//      exact single-step state) + viol detect: viol iff some point's new
//      n1 == DD(b2) while its old DD > DD(b2) (the only way any point can
//      reach b2's key value; pre-existing equals have larger orig => lose
//      first-occurrence to b2 by the global-#2 key argument). Block-OR via
//      LDS flag + 2nd barrier (dual rounds only). If clean: emit b2, apply
//      stage2 min(DD,n2) (bitwise == sequential update). If viol: fall back
//      to single-step -- state already correct, NO rollback needed.
//  (3) per-lane chunk prune covers BOTH queries (skip => both stages no-op,
//      margin proof as rounds 1-6); winner/b2 chunks have lb=0 => active.
//  Also: 1024-thread sort (3-level k-d x->y->z), ascending-orig 16-chunks.

#define PAIRS8_X(X) X(0) X(1) X(2) X(3) X(4) X(5) X(6) X(7)

// u64 max-combine with DPP-shifted copy (old=0 is identity: keys >= 0)
#define DPP_MAX_STEP(key, CTRL) { \
        const u32 lo_  = (u32)(key); \
        const u32 hi_  = (u32)((key) >> 32); \
        const u32 lo2_ = (u32)__builtin_amdgcn_update_dpp(0, (int)lo_, (CTRL), 0xf, 0xf, false); \
        const u32 hi2_ = (u32)__builtin_amdgcn_update_dpp(0, (int)hi_, (CTRL), 0xf, 0xf, false); \
        const u64 ok_  = ((u64)hi2_ << 32) | lo2_; \
        (key) = (ok_ > (key)) ? ok_ : (key); \
    }

#define DPP_FMIN_STEP(v, CTRL) { \
        const int t_ = __builtin_amdgcn_update_dpp(__float_as_int(v), __float_as_int(v), (CTRL), 0xf, 0xf, false); \
        (v) = fminf((v), __int_as_float(t_)); \
    }
#define DPP_FMAX_STEP(v, CTRL) { \
        const int t_ = __builtin_amdgcn_update_dpp(__float_as_int(v), __float_as_int(v), (CTRL), 0xf, 0xf, false); \
        (v) = fmaxf((v), __int_as_float(t_)); \
    }
#define DPP_RED6(MACRO, v) \
        MACRO(v, 0x111) MACRO(v, 0x112) MACRO(v, 0x114) MACRO(v, 0x118) \
        MACRO(v, 0x142) MACRO(v, 0x143)

// full-wave max -> lane 63 (proven rounds 0-6)
#define CHAIN6_MAX(key) \
        DPP_MAX_STEP(key, 0x111) DPP_MAX_STEP(key, 0x112) \
        DPP_MAX_STEP(key, 0x114) DPP_MAX_STEP(key, 0x118) \
        DPP_MAX_STEP(key, 0x142) DPP_MAX_STEP(key, 0x143)

// in-row (16-lane) butterfly all-reduce max -> ALL lanes (proven round 6)
#define BFLY4_MAX(key) \
        DPP_MAX_STEP(key, 0xB1) DPP_MAX_STEP(key, 0x4E) \
        DPP_MAX_STEP(key, 0x141) DPP_MAX_STEP(key, 0x140)

// ---------------------------------------------------------------------------
// One-time spatial ordering kernel (1024 threads/block, one block per cloud).
// 3 bitonic passes (x full, y within 4096, z within 1024) -> exact k-d tiles;
// per-16-chunk ascending-orig re-sort (exact first-occurrence ties); emit
// reordered coords + slot-major u16 map [16][1024]. Map is a permutation;
// sort quality only affects pruning rate, never correctness.
// ---------------------------------------------------------------------------
#define BITONIC_PASS(KMAX) \
    for (u32 k = 2; k <= (u32)(KMAX); k <<= 1) { \
        for (u32 j = k >> 1; j; j >>= 1) { \
            __syncthreads(); \
            for (int s = 0; s < PTS / SORT_THREADS; ++s) { \
                const u32 i = (u32)(tid + s * SORT_THREADS); \
                const u32 p = i ^ j; \
                if (p > i) { \
                    const u32 a = keys[i], b = keys[p]; \
                    if (((i & k) == 0) == (a > b)) { keys[i] = b; keys[p] = a; } \
                } \
            } \
        } \
    } \
    __syncthreads();

__global__ __launch_bounds__(SORT_THREADS)
void sort_kernel(const float* __restrict__ pos, float* __restrict__ pos_s,
                 u16* __restrict__ mapT)
{
    __shared__ u32 keys[PTS];          // 64 KiB
    const int cloud = blockIdx.x;
    const int tid   = threadIdx.x;
    const int ln    = tid & 63;
    const size_t b3 = (size_t)cloud * PTS * 3;

    float mnx = 1e30f, mxx = -1e30f, mny = 1e30f, mxy = -1e30f;
    float mnz = 1e30f, mxz = -1e30f;
    for (int s = 0; s < PTS / SORT_THREADS; ++s) {
        const size_t o = b3 + (size_t)(tid + s * SORT_THREADS) * 3;
        const float x = pos[o + 0];
        const float y = pos[o + 1];
        const float z = pos[o + 2];
        mnx = fminf(mnx, x); mxx = fmaxf(mxx, x);
        mny = fminf(mny, y); mxy = fmaxf(mxy, y);
        mnz = fminf(mnz, z); mxz = fmaxf(mxz, z);
    }
    DPP_RED6(DPP_FMIN_STEP, mnx)
    DPP_RED6(DPP_FMAX_STEP, mxx)
    DPP_RED6(DPP_FMIN_STEP, mny)
    DPP_RED6(DPP_FMAX_STEP, mxy)
    DPP_RED6(DPP_FMIN_STEP, mnz)
    DPP_RED6(DPP_FMAX_STEP, mxz)
    float* red = (float*)keys;
    const int nw = SORT_THREADS / 64;
    if (ln == 63) {
        red[tid >> 6]          = mnx;
        red[nw + (tid >> 6)]   = mxx;
        red[2*nw + (tid >> 6)] = mny;
        red[3*nw + (tid >> 6)] = mxy;
        red[4*nw + (tid >> 6)] = mnz;
        red[5*nw + (tid >> 6)] = mxz;
    }
    __syncthreads();
    float xmin = red[0], xmax = red[nw], ymin = red[2*nw], ymax = red[3*nw];
    float zmin = red[4*nw], zmax = red[5*nw];
    for (int w = 1; w < nw; ++w) {
        xmin = fminf(xmin, red[w]);
        xmax = fmaxf(xmax, red[nw + w]);
        ymin = fminf(ymin, red[2*nw + w]);
        ymax = fmaxf(ymax, red[3*nw + w]);
        zmin = fminf(zmin, red[4*nw + w]);
        zmax = fmaxf(zmax, red[5*nw + w]);
    }
    __syncthreads();

    const float xscale = 262143.0f / fmaxf(xmax - xmin, 1e-30f);
    const float yscale = 262143.0f / fmaxf(ymax - ymin, 1e-30f);
    const float zscale = 262143.0f / fmaxf(zmax - zmin, 1e-30f);

    for (int s = 0; s < PTS / SORT_THREADS; ++s) {
        const int i = tid + s * SORT_THREADS;
        const float x = pos[b3 + (size_t)i * 3];
        const u32 q = (u32)fminf(fmaxf((x - xmin) * xscale, 0.0f), 262143.0f);
        keys[i] = (q << 14) | (u32)i;
    }
    BITONIC_PASS(PTS)

    for (int s = 0; s < PTS / SORT_THREADS; ++s) {
        const int i = tid + s * SORT_THREADS;
        const u32 orig = keys[i] & (u32)(PTS - 1);
        const float y = pos[b3 + (size_t)orig * 3 + 1];
        const u32 q = (u32)fminf(fmaxf((y - ymin) * yscale, 0.0f), 262143.0f);
        keys[i] = (q << 14) | orig;
    }
    BITONIC_PASS(4096u)

    for (int s = 0; s < PTS / SORT_THREADS; ++s) {
        const int i = tid + s * SORT_THREADS;
        const u32 orig = keys[i] & (u32)(PTS - 1);
        const float z = pos[b3 + (size_t)orig * 3 + 2];
        const u32 q = (u32)fminf(fmaxf((z - zmin) * zscale, 0.0f), 262143.0f);
        keys[i] = (q << 14) | orig;
    }
    BITONIC_PASS(1024u)

    // per-16-chunk ascending-orig re-sort (exact first-occurrence ties)
    {
        u32 loc[PPT];
        const int cb = tid * PPT;
        for (int s = 0; s < PPT; ++s) loc[s] = keys[cb + s] & (u32)(PTS - 1);
        for (int a = 1; a < PPT; ++a) {
            const u32 v = loc[a];
            int b = a;
            while (b > 0 && loc[b - 1] > v) { loc[b] = loc[b - 1]; --b; }
            loc[b] = v;
        }
        for (int s = 0; s < PPT; ++s) keys[cb + s] = loc[s];
    }
    __syncthreads();

    for (int s = 0; s < PTS / SORT_THREADS; ++s) {
        const int i = tid + s * SORT_THREADS;   // sorted position
        const u32 orig = keys[i];
        mapT[(size_t)cloud * PTS + (size_t)(i & (PPT - 1)) * FPS_THREADS + (i >> 4)] = (u16)orig;
        const size_t so = b3 + (size_t)i * 3;
        const size_t oo = b3 + (size_t)orig * 3;
        pos_s[so + 0] = pos[oo + 0];
        pos_s[so + 1] = pos[oo + 1];
        pos_s[so + 2] = pos[oo + 2];
    }
}

// ---------------------------------------------------------------------------
// Main FPS kernel (one block per cloud, 16 waves). SORTED=false fallback.
// ---------------------------------------------------------------------------
template<bool SORTED>
__global__ __launch_bounds__(FPS_THREADS)
__attribute__((amdgpu_waves_per_eu(4, 4)))
void fps_kernel(const float* __restrict__ pos,      // original (winner fetch, q0)
                const float* __restrict__ psrc,     // sorted coords (or == pos)
                const u16* __restrict__ mapT,       // slot-major orig map (or null)
                int* __restrict__ out)
{
#pragma clang fp contract(off)
    const int cloud = blockIdx.x;
    const int tid   = threadIdx.x;
    const int base  = cloud * PTS;
    const int wave  = tid >> 6;
    const int lane  = tid & 63;

    __shared__ u64 skA[2][NWAVES];
    __shared__ u64 skB[2][NWAVES];
    __shared__ u32 vflag[2];
    __shared__ __attribute__((aligned(16))) u16 mlds[PTS];   // [slot][thread]

    if (tid == 0) { vflag[0] = 0; vflag[1] = 0; }
    if constexpr (SORTED) {
        const uint4* src = (const uint4*)(mapT + (size_t)cloud * PTS);
        uint4* dst = (uint4*)mlds;
#pragma unroll
        for (int s = 0; s < PTS * 2 / 16 / FPS_THREADS; ++s)   // 2 iters
            dst[s * FPS_THREADS + tid] = src[s * FPS_THREADS + tid];
    }
    __syncthreads();

    // ---- query = point 0 of cloud (ORIGINAL order) ----
    const float q0x = pos[(size_t)base * 3 + 0];
    const float q0y = pos[(size_t)base * 3 + 1];
    const float q0z = pos[(size_t)base * 3 + 2];

    // ---- one-time vectorized load: 16 consecutive pts = 12 float4 ----
    const float4* pos4 = (const float4*)psrc;
    const int fo = cloud * (PTS * 3 / 4) + tid * (PPT * 3 / 4);

#define DECL(j) v2f XX##j, YY##j, ZZ##j, DD##j;
    PAIRS8_X(DECL)
#undef DECL

#define QUADLOAD(q, j0, j1) { \
        const float4 fa = pos4[fo + 3*(q) + 0]; \
        const float4 fb = pos4[fo + 3*(q) + 1]; \
        const float4 fc = pos4[fo + 3*(q) + 2]; \
        XX##j0 = (v2f){fa.x, fa.w}; \
        YY##j0 = (v2f){fa.y, fb.x}; \
        ZZ##j0 = (v2f){fa.z, fb.y}; \
        XX##j1 = (v2f){fb.z, fc.y}; \
        YY##j1 = (v2f){fb.w, fc.z}; \
        ZZ##j1 = (v2f){fc.x, fc.w}; }
    QUADLOAD(0, 0, 1) QUADLOAD(1, 2, 3) QUADLOAD(2, 4, 5) QUADLOAD(3, 6, 7)
#undef QUADLOAD

#define PIN8(a,b,c,d,e,g,h,k) asm volatile("" : "+v"(a),"+v"(b),"+v"(c),"+v"(d),"+v"(e),"+v"(g),"+v"(h),"+v"(k));
    PIN8(XX0, XX1, XX2, XX3, XX4, XX5, XX6, XX7)
    PIN8(YY0, YY1, YY2, YY3, YY4, YY5, YY6, YY7)
    PIN8(ZZ0, ZZ1, ZZ2, ZZ3, ZZ4, ZZ5, ZZ6, ZZ7)
#undef PIN8

    // ---- per-LANE chunk (16-pt) TRUE 3D bbox, pure register min/max ----
    float cxlo, cxhi, cylo, cyhi, czlo, czhi;
    {
        float mnx = fminf(XX0.x, XX0.y), mxx = fmaxf(XX0.x, XX0.y);
        float mny = fminf(YY0.x, YY0.y), mxy = fmaxf(YY0.x, YY0.y);
        float mnz = fminf(ZZ0.x, ZZ0.y), mxz = fmaxf(ZZ0.x, ZZ0.y);
#define MINMAX(j) { mnx = fminf(mnx, fminf(XX##j.x, XX##j.y)); \
                    mxx = fmaxf(mxx, fmaxf(XX##j.x, XX##j.y)); \
                    mny = fminf(mny, fminf(YY##j.x, YY##j.y)); \
                    mxy = fmaxf(mxy, fmaxf(YY##j.x, YY##j.y)); \
                    mnz = fminf(mnz, fminf(ZZ##j.x, ZZ##j.y)); \
                    mxz = fmaxf(mxz, fmaxf(ZZ##j.x, ZZ##j.y)); }
        MINMAX(1) MINMAX(2) MINMAX(3) MINMAX(4) MINMAX(5) MINMAX(6) MINMAX(7)
#undef MINMAX
        cxlo = mnx; cxhi = mxx; cylo = mny; cyhi = mxy; czlo = mnz; czhi = mxz;
    }

    // ---- init dists to point 0 (no argmax here; FINALIZE does it) ----
    {
        const v2f qx2 = {q0x, q0x}, qy2 = {q0y, q0y}, qz2 = {q0z, q0z};
#define INITP(j) { \
        v2f dx = XX##j - qx2; \
        v2f dy = YY##j - qy2; \
        v2f dz = ZZ##j - qz2; \
        DD##j = (dx * dx + dy * dy) + dz * dz; }
        PAIRS8_X(INITP)
#undef INITP
    }

    if (tid == 0) out[cloud * M] = base;   // first sample = point 0

    // ---- FINALIZE: chunk top-2 -> wave top-2 keys (cached, uniform) ----
    float bd, bd2; int bk, bk2;
    u32 c_hi, c_lo, k2_hi, k2_lo;
#define TOP2H(v, s) { \
        const bool c1 = (v) > bd; \
        const bool c2 = (v) > bd2; \
        const float nb2 = c1 ? bd : (c2 ? (v) : bd2); \
        const int   nk2 = c1 ? bk : (c2 ? (s) : bk2); \
        bd  = c1 ? (v) : bd;  bk  = c1 ? (s) : bk; \
        bd2 = nb2;            bk2 = nk2; }
#define TOP2P(j) TOP2H(DD##j.x, 2*(j)) TOP2H(DD##j.y, 2*(j)+1)
#define FINALIZE() { \
        bd = -1.0f; bk = 0; bd2 = -1.0f; bk2 = 0; \
        PAIRS8_X(TOP2P) \
        int bi_, bi2_; \
        if constexpr (SORTED) { bi_  = (int)mlds[(bk  << 10) + tid]; \
                                bi2_ = (int)mlds[(bk2 << 10) + tid]; } \
        else                  { bi_  = tid * PPT + bk; \
                                bi2_ = tid * PPT + bk2; } \
        const u64 key1  = ((u64)__float_as_uint(bd)  << 32) | (u32)(~bi_); \
        const u64 key2v = ((u64)__float_as_uint(bd2) << 32) | (u32)(~bi2_); \
        u64 t_ = key1; \
        CHAIN6_MAX(t_) \
        c_hi = (u32)__builtin_amdgcn_readlane((int)(u32)(t_ >> 32), 63); \
        c_lo = (u32)__builtin_amdgcn_readlane((int)(u32)t_, 63); \
        const u64 cc_ = ((u64)c_hi << 32) | c_lo; \
        u64 sub_ = (key1 == cc_) ? key2v : key1; \
        CHAIN6_MAX(sub_) \
        k2_hi = (u32)__builtin_amdgcn_readlane((int)(u32)(sub_ >> 32), 63); \
        k2_lo = (u32)__builtin_amdgcn_readlane((int)(u32)sub_, 63); }

    FINALIZE()

    int i = 1, par = 0;
    while (i < M) {
        // ---- publish cached wave top-2 (always valid) + reset next flag ----
        if (lane == 0) {
            skA[par][wave] = ((u64)c_hi << 32) | c_lo;
            skB[par][wave] = ((u64)k2_hi << 32) | k2_lo;
        }
        if (tid == 0) vflag[par ^ 1] = 0;
        __syncthreads();

        // ---- cross-wave exact top-2 ----
        const u64 a = skA[par][lane & 15];
        const u64 b = skB[par][lane & 15];
        u64 g1 = a;
        BFLY4_MAX(g1)                          // all lanes: global top-1
        const bool isw = (a == g1);
        u64 r_ = isw ? 0ull : a;
        BFLY4_MAX(r_)                          // max of wave-top1s excl. winner
        const unsigned long long ball = __ballot(isw && (lane < 16));
        const int ws = (int)__ffsll(ball) - 1; // winner's wave (unique keys)
        const u32 bwlo = (u32)__builtin_amdgcn_readlane((int)(u32)b, ws);
        const u32 bwhi = (u32)__builtin_amdgcn_readlane((int)(u32)(b >> 32), ws);
        const u64 k2w = ((u64)bwhi << 32) | bwlo;   // winner wave's #2
        const u64 g2 = (k2w > r_) ? k2w : r_;       // exact global #2

        const u32 g1lo_s = (u32)__builtin_amdgcn_readfirstlane((int)(u32)g1);
        const u32 g2lo_s = (u32)__builtin_amdgcn_readfirstlane((int)(u32)g2);
        const u32 g2hi_s = (u32)__builtin_amdgcn_readfirstlane((int)(u32)(g2 >> 32));
        const int wi1 = (int)(~g1lo_s);
        const int wi2 = (int)(~g2lo_s);
        if (tid == 0) out[cloud * M + i] = base + wi1;

        // ---- winner + runner-up coords (uniform -> s_load) ----
        const float* p1 = pos + (size_t)(base + wi1) * 3;
        const float qx = p1[0], qy = p1[1], qz = p1[2];
        const float* p2 = pos + (size_t)(base + wi2) * 3;
        const float bx = p2[0], by = p2[1], bz = p2[2];

        // ---- speculative test: EXACT op-form match with the update ----
        const float ddb2 = __uint_as_float(g2hi_s);
        const float tdx = bx - qx, tdy = by - qy, tdz = bz - qz;
        const float d2q = (tdx * tdx + tdy * tdy) + tdz * tdz;
        const bool dual = (d2q >= ddb2) && (i + 1 < M);

        const float q2x = dual ? bx : qx;
        const float q2y = dual ? by : qy;
        const float q2z = dual ? bz : qz;

        // ---- per-lane chunk prune for BOTH queries ----
        const float ax = fmaxf(fmaxf(cxlo - qx, qx - cxhi), 0.0f);
        const float ay = fmaxf(fmaxf(cylo - qy, qy - cyhi), 0.0f);
        const float az = fmaxf(fmaxf(czlo - qz, qz - czhi), 0.0f);
        const float lb1 = (ax * ax + ay * ay) + az * az;
        const float ex = fmaxf(fmaxf(cxlo - q2x, q2x - cxhi), 0.0f);
        const float ey = fmaxf(fmaxf(cylo - q2y, q2y - cyhi), 0.0f);
        const float ez = fmaxf(fmaxf(czlo - q2z, q2z - czhi), 0.0f);
        const float lb2 = (ex * ex + ey * ey) + ez * ez;
        const bool skip = (lb1 * 0.9999f > bd) && (lb2 * 0.9999f > bd);
        const bool act = !__all(skip);

        // ---- stage 1: w1-only update (always exact single-step state) ----
        int viol = 0;
        if (act) {
            const v2f qxa = {qx, qx}, qya = {qy, qy}, qza = {qz, qz};
#define UPD1V(j) { \
        v2f dx = XX##j - qxa; v2f dy = YY##j - qya; v2f dz = ZZ##j - qza; \
        v2f n1 = (dx * dx + dy * dy) + dz * dz; \
        viol |= ((n1.x == ddb2) && (DD##j.x > ddb2)) ? 1 : 0; \
        viol |= ((n1.y == ddb2) && (DD##j.y > ddb2)) ? 1 : 0; \
        DD##j.x = fminf(DD##j.x, n1.x); \
        DD##j.y = fminf(DD##j.y, n1.y); }
#define UPD1P(j) { \
        v2f dx = XX##j - qxa; v2f dy = YY##j - qya; v2f dz = ZZ##j - qza; \
        v2f n1 = (dx * dx + dy * dy) + dz * dz; \
        DD##j.x = fminf(DD##j.x, n1.x); \
        DD##j.y = fminf(DD##j.y, n1.y); }
            if (dual) { PAIRS8_X(UPD1V) } else { PAIRS8_X(UPD1P) }
#undef UPD1V
#undef UPD1P
        }

        // ---- dual commit: block-wide viol check, then stage 2 ----
        bool commit2 = false;
        if (dual) {                                  // block-uniform branch
            if (act && __any(viol) && lane == 0) vflag[par] = 1;
            __syncthreads();
            commit2 = (vflag[par] == 0);
            if (commit2) {
                if (tid == 0) out[cloud * M + i + 1] = base + wi2;
                if (act) {
                    const v2f qxb = {q2x, q2x}, qyb = {q2y, q2y}, qzb = {q2z, q2z};
#define UPD2(j) { \
        v2f dx = XX##j - qxb; v2f dy = YY##j - qyb; v2f dz = ZZ##j - qzb; \
        v2f n2 = (dx * dx + dy * dy) + dz * dz; \
        DD##j.x = fminf(DD##j.x, n2.x); \
        DD##j.y = fminf(DD##j.y, n2.y); }
                    PAIRS8_X(UPD2)
#undef UPD2
                }
            }
        }

        // ---- recompute chunk/wave top-2 keys on final DD ----
        if (act) FINALIZE()

        par ^= 1;
        i += commit2 ? 2 : 1;
    }
}

extern "C" void kernel_launch(void* const* d_in, const int* in_sizes, int n_in,
                              void* d_out, int out_size, void* d_ws, size_t ws_size,
                              hipStream_t stream) {
    const float* pos = (const float*)d_in[0];
    int* out = (int*)d_out;

    const size_t pos_s_bytes = (size_t)N_CLOUDS * PTS * 3 * sizeof(float);   // 3 MiB
    const size_t map_bytes   = (size_t)N_CLOUDS * PTS * sizeof(u16);         // 0.5 MiB
    if (d_ws && ws_size >= pos_s_bytes + map_bytes) {
        float* pos_s = (float*)d_ws;
        u16*   mapT  = (u16*)((char*)d_ws + pos_s_bytes);
        sort_kernel<<<N_CLOUDS, SORT_THREADS, 0, stream>>>(pos, pos_s, mapT);
        fps_kernel<true><<<N_CLOUDS, FPS_THREADS, 0, stream>>>(pos, pos_s, mapT, out);
    } else {
        fps_kernel<false><<<N_CLOUDS, FPS_THREADS, 0, stream>>>(pos, pos, nullptr, out);
    }
}

// Round 9
// 4313.272 us; speedup vs baseline: 1.8590x; 1.8590x over previous
//
#include <hip/hip_runtime.h>

#define N_CLOUDS 16
#define PTS      16384
#define M        4096
#define FPS_THREADS  1024
#define NWAVES   (FPS_THREADS / 64)   // 16 waves
#define PPT      16                   // consecutive (sorted-order) points per thread
#define SORT_THREADS 1024

typedef float v2f __attribute__((ext_vector_type(2)));
typedef unsigned long long u64;
typedef unsigned int u32;
typedef unsigned short u16;

// Round-13: single-step loop (r3 structure, dual-step abandoned per r8
// measurement) with the serial head shortened:
//  (1) winner coords via LDS: the owning lane PREFETCHES its candidate's
//      coords from pos at FINALIZE time (global-load latency hides behind
//      the loop tail + barrier) and publishes them next to the wave key;
//      the post-barrier path is ds_read + readlane instead of
//      reduce->readlane->s_load(L2 ~200-400cy). Coords are bit-exact pos[]
//      values (same as the old s_load).
//  (2) f32/u32 fast-path reduces: max the 32-bit dist field (dpp mov +
//      v_max_u32 per step) + ballot-equality to find the owner; on a
//      bitwise dist tie (rare) fall back to the proven exact u64 chain.
//      Unique max => identical winner; tie => identical chain. Bit-exact.
//  (3) per-lane chunk prune (16-pt true bbox vs own bd = chunk maxDD),
//      margin 1e-4 >> fp err ~5e-7; winner's chunk has lb=0 => wave active.
//  (4) 3-pass k-d sort (x4 -> y4 -> z4) at 1024 threads (~300us); per-16-
//      chunk ascending-orig re-sort keeps first-occurrence ties bit-exact.

#define PAIRS8_X(X) X(0) X(1) X(2) X(3) X(4) X(5) X(6) X(7)

// u64 max-combine with DPP-shifted copy (old=0 is identity: keys >= 0)
#define DPP_MAX_STEP(key, CTRL) { \
        const u32 lo_  = (u32)(key); \
        const u32 hi_  = (u32)((key) >> 32); \
        const u32 lo2_ = (u32)__builtin_amdgcn_update_dpp(0, (int)lo_, (CTRL), 0xf, 0xf, false); \
        const u32 hi2_ = (u32)__builtin_amdgcn_update_dpp(0, (int)hi_, (CTRL), 0xf, 0xf, false); \
        const u64 ok_  = ((u64)hi2_ << 32) | lo2_; \
        (key) = (ok_ > (key)) ? ok_ : (key); \
    }

// u32 max-combine with DPP-shifted copy (old=0 identity: values >= 0)
#define DPP_MAXU_STEP(v, CTRL) { \
        const u32 t_ = (u32)__builtin_amdgcn_update_dpp(0, (int)(v), (CTRL), 0xf, 0xf, false); \
        (v) = (t_ > (v)) ? t_ : (v); \
    }

#define DPP_FMIN_STEP(v, CTRL) { \
        const int t_ = __builtin_amdgcn_update_dpp(__float_as_int(v), __float_as_int(v), (CTRL), 0xf, 0xf, false); \
        (v) = fminf((v), __int_as_float(t_)); \
    }
#define DPP_FMAX_STEP(v, CTRL) { \
        const int t_ = __builtin_amdgcn_update_dpp(__float_as_int(v), __float_as_int(v), (CTRL), 0xf, 0xf, false); \
        (v) = fmaxf((v), __int_as_float(t_)); \
    }
#define DPP_RED6(MACRO, v) \
        MACRO(v, 0x111) MACRO(v, 0x112) MACRO(v, 0x114) MACRO(v, 0x118) \
        MACRO(v, 0x142) MACRO(v, 0x143)

// full-wave max -> lane 63 (proven chain)
#define CHAIN6_MAX(key) \
        DPP_MAX_STEP(key, 0x111) DPP_MAX_STEP(key, 0x112) \
        DPP_MAX_STEP(key, 0x114) DPP_MAX_STEP(key, 0x118) \
        DPP_MAX_STEP(key, 0x142) DPP_MAX_STEP(key, 0x143)
#define CHAIN6_MAXU(v) \
        DPP_MAXU_STEP(v, 0x111) DPP_MAXU_STEP(v, 0x112) \
        DPP_MAXU_STEP(v, 0x114) DPP_MAXU_STEP(v, 0x118) \
        DPP_MAXU_STEP(v, 0x142) DPP_MAXU_STEP(v, 0x143)

// in-row (16-lane) butterfly all-reduce max -> ALL lanes (proven round 6)
#define BFLY4_MAX(key) \
        DPP_MAX_STEP(key, 0xB1) DPP_MAX_STEP(key, 0x4E) \
        DPP_MAX_STEP(key, 0x141) DPP_MAX_STEP(key, 0x140)
#define BFLY4_MAXU(v) \
        DPP_MAXU_STEP(v, 0xB1) DPP_MAXU_STEP(v, 0x4E) \
        DPP_MAXU_STEP(v, 0x141) DPP_MAXU_STEP(v, 0x140)

// ---------------------------------------------------------------------------
// One-time spatial ordering kernel (1024 threads/block, one block per cloud).
// 3 bitonic passes (x full, y within 4096, z within 1024) -> exact k-d tiles;
// per-16-chunk ascending-orig re-sort (exact first-occurrence ties); emit
// reordered coords + slot-major u16 map [16][1024]. Map is a permutation;
// sort quality only affects pruning rate, never correctness. (Ran clean in r8.)
// ---------------------------------------------------------------------------
#define BITONIC_PASS(KMAX) \
    for (u32 k = 2; k <= (u32)(KMAX); k <<= 1) { \
        for (u32 j = k >> 1; j; j >>= 1) { \
            __syncthreads(); \
            for (int s = 0; s < PTS / SORT_THREADS; ++s) { \
                const u32 i = (u32)(tid + s * SORT_THREADS); \
                const u32 p = i ^ j; \
                if (p > i) { \
                    const u32 a = keys[i], b = keys[p]; \
                    if (((i & k) == 0) == (a > b)) { keys[i] = b; keys[p] = a; } \
                } \
            } \
        } \
    } \
    __syncthreads();

__global__ __launch_bounds__(SORT_THREADS)
void sort_kernel(const float* __restrict__ pos, float* __restrict__ pos_s,
                 u16* __restrict__ mapT)
{
    __shared__ u32 keys[PTS];          // 64 KiB
    const int cloud = blockIdx.x;
    const int tid   = threadIdx.x;
    const int ln    = tid & 63;
    const size_t b3 = (size_t)cloud * PTS * 3;

    float mnx = 1e30f, mxx = -1e30f, mny = 1e30f, mxy = -1e30f;
    float mnz = 1e30f, mxz = -1e30f;
    for (int s = 0; s < PTS / SORT_THREADS; ++s) {
        const size_t o = b3 + (size_t)(tid + s * SORT_THREADS) * 3;
        const float x = pos[o + 0];
        const float y = pos[o + 1];
        const float z = pos[o + 2];
        mnx = fminf(mnx, x); mxx = fmaxf(mxx, x);
        mny = fminf(mny, y); mxy = fmaxf(mxy, y);
        mnz = fminf(mnz, z); mxz = fmaxf(mxz, z);
    }
    DPP_RED6(DPP_FMIN_STEP, mnx)
    DPP_RED6(DPP_FMAX_STEP, mxx)
    DPP_RED6(DPP_FMIN_STEP, mny)
    DPP_RED6(DPP_FMAX_STEP, mxy)
    DPP_RED6(DPP_FMIN_STEP, mnz)
    DPP_RED6(DPP_FMAX_STEP, mxz)
    float* red = (float*)keys;
    const int nw = SORT_THREADS / 64;
    if (ln == 63) {
        red[tid >> 6]          = mnx;
        red[nw + (tid >> 6)]   = mxx;
        red[2*nw + (tid >> 6)] = mny;
        red[3*nw + (tid >> 6)] = mxy;
        red[4*nw + (tid >> 6)] = mnz;
        red[5*nw + (tid >> 6)] = mxz;
    }
    __syncthreads();
    float xmin = red[0], xmax = red[nw], ymin = red[2*nw], ymax = red[3*nw];
    float zmin = red[4*nw], zmax = red[5*nw];
    for (int w = 1; w < nw; ++w) {
        xmin = fminf(xmin, red[w]);
        xmax = fmaxf(xmax, red[nw + w]);
        ymin = fminf(ymin, red[2*nw + w]);
        ymax = fmaxf(ymax, red[3*nw + w]);
        zmin = fminf(zmin, red[4*nw + w]);
        zmax = fmaxf(zmax, red[5*nw + w]);
    }
    __syncthreads();

    const float xscale = 262143.0f / fmaxf(xmax - xmin, 1e-30f);
    const float yscale = 262143.0f / fmaxf(ymax - ymin, 1e-30f);
    const float zscale = 262143.0f / fmaxf(zmax - zmin, 1e-30f);

    for (int s = 0; s < PTS / SORT_THREADS; ++s) {
        const int i = tid + s * SORT_THREADS;
        const float x = pos[b3 + (size_t)i * 3];
        const u32 q = (u32)fminf(fmaxf((x - xmin) * xscale, 0.0f), 262143.0f);
        keys[i] = (q << 14) | (u32)i;
    }
    BITONIC_PASS(PTS)

    for (int s = 0; s < PTS / SORT_THREADS; ++s) {
        const int i = tid + s * SORT_THREADS;
        const u32 orig = keys[i] & (u32)(PTS - 1);
        const float y = pos[b3 + (size_t)orig * 3 + 1];
        const u32 q = (u32)fminf(fmaxf((y - ymin) * yscale, 0.0f), 262143.0f);
        keys[i] = (q << 14) | orig;
    }
    BITONIC_PASS(4096u)

    for (int s = 0; s < PTS / SORT_THREADS; ++s) {
        const int i = tid + s * SORT_THREADS;
        const u32 orig = keys[i] & (u32)(PTS - 1);
        const float z = pos[b3 + (size_t)orig * 3 + 2];
        const u32 q = (u32)fminf(fmaxf((z - zmin) * zscale, 0.0f), 262143.0f);
        keys[i] = (q << 14) | orig;
    }
    BITONIC_PASS(1024u)

    // per-16-chunk ascending-orig re-sort (exact first-occurrence ties)
    {
        u32 loc[PPT];
        const int cb = tid * PPT;
        for (int s = 0; s < PPT; ++s) loc[s] = keys[cb + s] & (u32)(PTS - 1);
        for (int a = 1; a < PPT; ++a) {
            const u32 v = loc[a];
            int b = a;
            while (b > 0 && loc[b - 1] > v) { loc[b] = loc[b - 1]; --b; }
            loc[b] = v;
        }
        for (int s = 0; s < PPT; ++s) keys[cb + s] = loc[s];
    }
    __syncthreads();

    for (int s = 0; s < PTS / SORT_THREADS; ++s) {
        const int i = tid + s * SORT_THREADS;   // sorted position
        const u32 orig = keys[i];
        mapT[(size_t)cloud * PTS + (size_t)(i & (PPT - 1)) * FPS_THREADS + (i >> 4)] = (u16)orig;
        const size_t so = b3 + (size_t)i * 3;
        const size_t oo = b3 + (size_t)orig * 3;
        pos_s[so + 0] = pos[oo + 0];
        pos_s[so + 1] = pos[oo + 1];
        pos_s[so + 2] = pos[oo + 2];
    }
}

// ---------------------------------------------------------------------------
// Main FPS kernel (one block per cloud, 16 waves). SORTED=false fallback.
// ---------------------------------------------------------------------------
template<bool SORTED>
__global__ __launch_bounds__(FPS_THREADS)
__attribute__((amdgpu_waves_per_eu(4, 4)))
void fps_kernel(const float* __restrict__ pos,      // original (coords, q0)
                const float* __restrict__ psrc,     // sorted coords (or == pos)
                const u16* __restrict__ mapT,       // slot-major orig map (or null)
                int* __restrict__ out)
{
#pragma clang fp contract(off)
    const int cloud = blockIdx.x;
    const int tid   = threadIdx.x;
    const int base  = cloud * PTS;
    const int wave  = tid >> 6;
    const int lane  = tid & 63;

    __shared__ u64 skey[2][NWAVES];
    __shared__ float scx[2][NWAVES], scy[2][NWAVES], scz[2][NWAVES];
    __shared__ __attribute__((aligned(16))) u16 mlds[PTS];   // [slot][thread]

    if constexpr (SORTED) {
        const uint4* src = (const uint4*)(mapT + (size_t)cloud * PTS);
        uint4* dst = (uint4*)mlds;
#pragma unroll
        for (int s = 0; s < PTS * 2 / 16 / FPS_THREADS; ++s)   // 2 iters
            dst[s * FPS_THREADS + tid] = src[s * FPS_THREADS + tid];
        __syncthreads();
    }

    // ---- query = point 0 of cloud (ORIGINAL order) ----
    const float q0x = pos[(size_t)base * 3 + 0];
    const float q0y = pos[(size_t)base * 3 + 1];
    const float q0z = pos[(size_t)base * 3 + 2];

    // ---- one-time vectorized load: 16 consecutive pts = 12 float4 ----
    const float4* pos4 = (const float4*)psrc;
    const int fo = cloud * (PTS * 3 / 4) + tid * (PPT * 3 / 4);

#define DECL(j) v2f XX##j, YY##j, ZZ##j, DD##j;
    PAIRS8_X(DECL)
#undef DECL

#define QUADLOAD(q, j0, j1) { \
        const float4 fa = pos4[fo + 3*(q) + 0]; \
        const float4 fb = pos4[fo + 3*(q) + 1]; \
        const float4 fc = pos4[fo + 3*(q) + 2]; \
        XX##j0 = (v2f){fa.x, fa.w}; \
        YY##j0 = (v2f){fa.y, fb.x}; \
        ZZ##j0 = (v2f){fa.z, fb.y}; \
        XX##j1 = (v2f){fb.z, fc.y}; \
        YY##j1 = (v2f){fb.w, fc.z}; \
        ZZ##j1 = (v2f){fc.x, fc.w}; }
    QUADLOAD(0, 0, 1) QUADLOAD(1, 2, 3) QUADLOAD(2, 4, 5) QUADLOAD(3, 6, 7)
#undef QUADLOAD

#define PIN8(a,b,c,d,e,g,h,k) asm volatile("" : "+v"(a),"+v"(b),"+v"(c),"+v"(d),"+v"(e),"+v"(g),"+v"(h),"+v"(k));
    PIN8(XX0, XX1, XX2, XX3, XX4, XX5, XX6, XX7)
    PIN8(YY0, YY1, YY2, YY3, YY4, YY5, YY6, YY7)
    PIN8(ZZ0, ZZ1, ZZ2, ZZ3, ZZ4, ZZ5, ZZ6, ZZ7)
#undef PIN8

    // ---- per-LANE chunk (16-pt) TRUE 3D bbox, pure register min/max ----
    float cxlo, cxhi, cylo, cyhi, czlo, czhi;
    {
        float mnx = fminf(XX0.x, XX0.y), mxx = fmaxf(XX0.x, XX0.y);
        float mny = fminf(YY0.x, YY0.y), mxy = fmaxf(YY0.x, YY0.y);
        float mnz = fminf(ZZ0.x, ZZ0.y), mxz = fmaxf(ZZ0.x, ZZ0.y);
#define MINMAX(j) { mnx = fminf(mnx, fminf(XX##j.x, XX##j.y)); \
                    mxx = fmaxf(mxx, fmaxf(XX##j.x, XX##j.y)); \
                    mny = fminf(mny, fminf(YY##j.x, YY##j.y)); \
                    mxy = fmaxf(mxy, fmaxf(YY##j.x, YY##j.y)); \
                    mnz = fminf(mnz, fminf(ZZ##j.x, ZZ##j.y)); \
                    mxz = fmaxf(mxz, fmaxf(ZZ##j.x, ZZ##j.y)); }
        MINMAX(1) MINMAX(2) MINMAX(3) MINMAX(4) MINMAX(5) MINMAX(6) MINMAX(7)
#undef MINMAX
        cxlo = mnx; cxhi = mxx; cylo = mny; cyhi = mxy; czlo = mnz; czhi = mxz;
    }

    // ---- init dists to point 0 + lane-local argmax ----
    float bd = -1.0f;
    int   bk = 0;
    {
        const v2f qx2 = {q0x, q0x}, qy2 = {q0y, q0y}, qz2 = {q0z, q0z};
#define INITP(j) { \
        v2f dx = XX##j - qx2; \
        v2f dy = YY##j - qy2; \
        v2f dz = ZZ##j - qz2; \
        v2f nd = (dx * dx + dy * dy) + dz * dz; \
        DD##j = nd; \
        if (nd.x > bd) { bd = nd.x; bk = 2*(j); } \
        if (nd.y > bd) { bd = nd.y; bk = 2*(j) + 1; } \
    }
        PAIRS8_X(INITP)
#undef INITP
    }

    if (tid == 0) out[cloud * M] = base;   // first sample = point 0

    // ---- FINALIZE: wave key via u32 fast path (+exact u64 tie fallback),
    //      owner lane prefetches its candidate's coords from pos ----
    u32 c_hi, c_lo;
    bool isown;
    float qpx = 0.0f, qpy = 0.0f, qpz = 0.0f;
#define FINALIZE() { \
        int bi_; \
        if constexpr (SORTED) bi_ = (int)mlds[(bk << 10) + tid]; \
        else                  bi_ = tid * PPT + bk; \
        const u32 nbi_ = ~(u32)bi_; \
        const u32 db_  = __float_as_uint(bd); \
        u32 mx_ = db_; \
        CHAIN6_MAXU(mx_) \
        const u32 wmax_ = (u32)__builtin_amdgcn_readlane((int)mx_, 63); \
        const unsigned long long bl_ = __ballot(db_ == wmax_); \
        if (__popcll(bl_) == 1) { \
            const int ow_ = (int)__ffsll(bl_) - 1; \
            c_hi = wmax_; \
            c_lo = (u32)__builtin_amdgcn_readlane((int)nbi_, ow_); \
            isown = (lane == ow_); \
        } else { \
            u64 key_ = ((u64)db_ << 32) | nbi_; \
            CHAIN6_MAX(key_) \
            c_hi = (u32)__builtin_amdgcn_readlane((int)(u32)(key_ >> 32), 63); \
            c_lo = (u32)__builtin_amdgcn_readlane((int)(u32)key_, 63); \
            isown = (db_ == c_hi) && (nbi_ == c_lo); \
        } \
        if (isown) { \
            const float* pp_ = pos + (size_t)(base + bi_) * 3; \
            qpx = pp_[0]; qpy = pp_[1]; qpz = pp_[2]; \
        } \
    }

    FINALIZE()

    int par = 0;
    for (int i = 1; i < M; ++i) {
        // ---- publish cached wave key + owner's candidate coords ----
        if (lane == 0) skey[par][wave] = ((u64)c_hi << 32) | c_lo;
        if (isown) {
            scx[par][wave] = qpx;
            scy[par][wave] = qpy;
            scz[par][wave] = qpz;
        }
        __syncthreads();

        // ---- cross-wave winner: u32 fast path + exact u64 fallback ----
        const u64 a  = skey[par][lane & 15];
        const float kx = scx[par][lane & 15];
        const float ky = scy[par][lane & 15];
        const float kz = scz[par][lane & 15];

        const u32 ahi = (u32)(a >> 32);
        u32 mh = ahi;
        BFLY4_MAXU(mh)                          // all lanes: max dist bits
        const unsigned long long ball = __ballot(ahi == mh) & 0xFFFFull;
        int ws; u32 wlo;
        if (__popcll(ball) == 1) {
            ws  = (int)__ffsll(ball) - 1;
            wlo = (u32)__builtin_amdgcn_readlane((int)(u32)a, ws);
        } else {
            u64 g = a;
            BFLY4_MAX(g)                        // exact u64 tie resolution
            const unsigned long long b2 = __ballot(a == g) & 0xFFFFull;
            ws  = (int)__ffsll(b2) - 1;
            wlo = (u32)__builtin_amdgcn_readfirstlane((int)(u32)g);
        }
        if (tid == 0) out[cloud * M + i] = base + (int)(~wlo);

        // ---- winner coords from LDS (bit-exact pos[] values) ----
        const float qx = __int_as_float(__builtin_amdgcn_readlane(__float_as_int(kx), ws));
        const float qy = __int_as_float(__builtin_amdgcn_readlane(__float_as_int(ky), ws));
        const float qz = __int_as_float(__builtin_amdgcn_readlane(__float_as_int(kz), ws));

        // ---- per-lane chunk prune (provable no-op => skip wave) ----
        const float ax = fmaxf(fmaxf(cxlo - qx, qx - cxhi), 0.0f);
        const float ay = fmaxf(fmaxf(cylo - qy, qy - cyhi), 0.0f);
        const float az = fmaxf(fmaxf(czlo - qz, qz - czhi), 0.0f);
        const float lb = (ax * ax + ay * ay) + az * az;
        if (!__all(lb * 0.9999f > bd)) {
            const v2f qx2 = {qx, qx}, qy2 = {qy, qy}, qz2 = {qz, qz};
            bd = -1.0f; bk = 0;
#define UPD(j) { \
        v2f dx = XX##j - qx2; \
        v2f dy = YY##j - qy2; \
        v2f dz = ZZ##j - qz2; \
        v2f nd = (dx * dx + dy * dy) + dz * dz; \
        DD##j.x = fminf(DD##j.x, nd.x); \
        DD##j.y = fminf(DD##j.y, nd.y); \
        if (DD##j.x > bd) { bd = DD##j.x; bk = 2*(j); } \
        if (DD##j.y > bd) { bd = DD##j.y; bk = 2*(j) + 1; } \
    }
            PAIRS8_X(UPD)
#undef UPD
            FINALIZE()
        }
        // skipped: DD/bd/bk/c_*/isown/qp* unchanged -- provably identical

        par ^= 1;
    }
}

extern "C" void kernel_launch(void* const* d_in, const int* in_sizes, int n_in,
                              void* d_out, int out_size, void* d_ws, size_t ws_size,
                              hipStream_t stream) {
    const float* pos = (const float*)d_in[0];
    int* out = (int*)d_out;

    const size_t pos_s_bytes = (size_t)N_CLOUDS * PTS * 3 * sizeof(float);   // 3 MiB
    const size_t map_bytes   = (size_t)N_CLOUDS * PTS * sizeof(u16);         // 0.5 MiB
    if (d_ws && ws_size >= pos_s_bytes + map_bytes) {
        float* pos_s = (float*)d_ws;
        u16*   mapT  = (u16*)((char*)d_ws + pos_s_bytes);
        sort_kernel<<<N_CLOUDS, SORT_THREADS, 0, stream>>>(pos, pos_s, mapT);
        fps_kernel<true><<<N_CLOUDS, FPS_THREADS, 0, stream>>>(pos, pos_s, mapT, out);
    } else {
        fps_kernel<false><<<N_CLOUDS, FPS_THREADS, 0, stream>>>(pos, pos, nullptr, out);
    }
}